// Round 5
// baseline (26.725 us; speedup 1.0000x reference)
//
#include <hip/hip_runtime.h>

// Rate-1/2, K=7 non-recursive conv encoder, B x 4096 -> B x 8192.
// out0[t] = m[t]^m[t-2]^m[t-3]^m[t-5]^m[t-6]   (G1 = 1011011)
// out1[t] = m[t]^m[t-1]^m[t-2]^m[t-3]^m[t-6]   (G2 = 1111001)
// cw[b, 2t] = out0[t], cw[b, 2t+1] = out1[t]
//
// R5 = R4 with NORMAL stores (A/B isolating the nontemporal hint, which is
// suspected of causing R4's 23.6->25.5us regression). Keeps UNROLL=4
// two-phase load/compute structure for memory-level parallelism.

#define K_BITS 4096
#define F4_PER_ROW (K_BITS / 2)   // 2048 output float4s per row
#define UNROLL 4

typedef float floatx4 __attribute__((ext_vector_type(4)));

__device__ __forceinline__ unsigned bit_of(float v) {
    // v is exactly 0.0f or 1.0f -> exponent-bit0 (0x3F800000) is the value.
    return (__float_as_uint(v) >> 23) & 1u;
}

__global__ __launch_bounds__(256) void conv_encode_kernel(
        const float* __restrict__ in, float* __restrict__ out, int total_f4) {
    const int stride = gridDim.x * 256;
    const int f4_0   = blockIdx.x * 256 + threadIdx.x;

    floatx4 a[UNROLL], b[UNROLL];
    unsigned w[UNROLL];

    // Phase 1: issue all loads (independent chunks -> deep MLP).
#pragma unroll
    for (int u = 0; u < UNROLL; ++u) {
        const int f4  = f4_0 + u * stride;
        const int row = f4 >> 11;            // /2048
        const int idx = f4 & 2047;
        const int t0  = idx << 1;
        const float* p = in + (size_t)row * K_BITS;
        if (idx >= 3) {
            a[u] = *reinterpret_cast<const floatx4*>(p + t0 - 6);
            b[u] = *reinterpret_cast<const floatx4*>(p + t0 - 2);
            w[u] = 0xffffffffu;              // marker: fast path
        } else {
            unsigned ww = 0;
#pragma unroll
            for (int k = 0; k < 8; ++k) {
                const int t = t0 - 6 + k;
                if (t >= 0) ww |= bit_of(p[t]) << k;
            }
            w[u] = ww;                       // (never 0xffffffff: bits 8+ clear)
        }
    }

    // Phase 2: pack, encode, store (dense 64x16B per instruction).
#pragma unroll
    for (int u = 0; u < UNROLL; ++u) {
        unsigned ww;
        if (w[u] == 0xffffffffu) {
            ww =  bit_of(a[u].x)
               | (bit_of(a[u].y) << 1)
               | (bit_of(a[u].z) << 2)
               | (bit_of(a[u].w) << 3)
               | (bit_of(b[u].x) << 4)
               | (bit_of(b[u].y) << 5)
               | (bit_of(b[u].z) << 6)
               | (bit_of(b[u].w) << 7);
        } else {
            ww = w[u];
        }

        const unsigned y0 = (ww >> 6) ^ (ww >> 4) ^ (ww >> 3) ^ (ww >> 1) ^ ww;
        const unsigned y1 = (ww >> 6) ^ (ww >> 5) ^ (ww >> 4) ^ (ww >> 3) ^ ww;

        floatx4 o;
        o.x = (float)( y0       & 1u);
        o.y = (float)( y1       & 1u);
        o.z = (float)((y0 >> 1) & 1u);
        o.w = (float)((y1 >> 1) & 1u);

        const int f4 = f4_0 + u * stride;
        *reinterpret_cast<floatx4*>(out + (size_t)f4 * 4) = o;
    }
}

extern "C" void kernel_launch(void* const* d_in, const int* in_sizes, int n_in,
                              void* d_out, int out_size, void* d_ws, size_t ws_size,
                              hipStream_t stream) {
    const float* in = (const float*)d_in[0];   // [B, 4096] of 0.0/1.0
    float* out = (float*)d_out;                // [B, 8192]

    const int B = in_sizes[0] / K_BITS;        // 2048
    const int total_f4 = B * F4_PER_ROW;       // 4.19M output float4s
    const int threads = total_f4 / UNROLL;     // exact: B*2048 % 4 == 0
    const int blocks = threads / 256;

    conv_encode_kernel<<<blocks, 256, 0, stream>>>(in, out, total_f4);
}

// Round 6
// 21.984 us; speedup vs baseline: 1.2157x; 1.2157x over previous
//
#include <hip/hip_runtime.h>

// Rate-1/2, K=7 non-recursive conv encoder, B x 4096 -> B x 8192.
// out0[t] = m[t]^m[t-2]^m[t-3]^m[t-5]^m[t-6]   (G1 = 1011011)
// out1[t] = m[t]^m[t-1]^m[t-2]^m[t-3]^m[t-6]   (G2 = 1111001)
// cw[b, 2t] = out0[t], cw[b, 2t+1] = out1[t]
//
// R6: ballot-packed input. One wave = 128 time steps. Each lane loads ONE
// input float (dense 256B dword load per wave); __ballot packs 64 time bits
// into a wave-uniform u64. Whole 134-bit window string lives in 3 SGPR u64s.
// Per-lane funnel shift extracts its 8-bit window; store is the same dense
// 64x16B float4 as R2. Read path: 0.75KB/wave vs R2's 2KB/wave.

#define K_BITS 4096

typedef float floatx4 __attribute__((ext_vector_type(4)));

__global__ __launch_bounds__(256) void conv_encode_kernel(
        const float* __restrict__ in, float* __restrict__ out) {
    const int gtid = blockIdx.x * 256 + threadIdx.x;
    const int wave = gtid >> 6;            // global wave id
    const int lane = threadIdx.x & 63;

    // 32 waves per row; each wave owns 128 consecutive time steps.
    const int row = wave >> 5;
    const int wt  = (wave & 31) << 7;      // base time step within row
    const float* p = in + (size_t)row * K_BITS;

    const float x0 = p[wt + lane];
    const float x1 = p[wt + 64 + lane];
    const unsigned long long s0 = __ballot(x0 != 0.0f);  // m[wt+0 .. wt+63]
    const unsigned long long s1 = __ballot(x1 != 0.0f);  // m[wt+64 .. wt+127]

    unsigned long long hist = 0;           // m[wt-6 .. wt-1], zero at row start
    if (wt > 0) {
        const float xh = p[wt - 64 + lane];
        hist = __ballot(xh != 0.0f) >> 58; // top 6 lanes
    }

    // String bit i (i = 0..133) = m[wt + i - 6].
    const unsigned long long A = (s0 << 6) | hist;         // bits 0..63
    const unsigned long long B = (s0 >> 58) | (s1 << 6);   // bits 64..127
    const unsigned long long C = (s1 >> 58);               // bits 128..133

    // Lane l emits times wt+2l, wt+2l+1; needs string bits 2l .. 2l+7.
    const unsigned s = (2 * lane) & 63;
    const unsigned long long lo = (lane < 32) ? A : B;
    const unsigned long long hi = (lane < 32) ? B : C;
    // w bit k = string bit (2*lane + k); safe 128-bit funnel (s in 0..62).
    const unsigned w =
        (unsigned)((lo >> s) | ((hi << (63 - s)) << 1));

    const unsigned y0 = (w >> 6) ^ (w >> 4) ^ (w >> 3) ^ (w >> 1) ^ w;
    const unsigned y1 = (w >> 6) ^ (w >> 5) ^ (w >> 4) ^ (w >> 3) ^ w;

    floatx4 o;
    o.x = (float)( y0       & 1u);
    o.y = (float)( y1       & 1u);
    o.z = (float)((y0 >> 1) & 1u);
    o.w = (float)((y1 >> 1) & 1u);

    // Wave's 64 lanes cover 64 consecutive output float4s (same as R2: tid*4).
    *reinterpret_cast<floatx4*>(out + (size_t)gtid * 4) = o;
}

extern "C" void kernel_launch(void* const* d_in, const int* in_sizes, int n_in,
                              void* d_out, int out_size, void* d_ws, size_t ws_size,
                              hipStream_t stream) {
    const float* in = (const float*)d_in[0];   // [B, 4096] of 0.0/1.0
    float* out = (float*)d_out;                // [B, 8192]

    const int B = in_sizes[0] / K_BITS;        // 2048
    const int total_threads = B * (K_BITS / 2);  // one float4 out per thread
    const int blocks = total_threads / 256;      // 16384

    conv_encode_kernel<<<blocks, 256, 0, stream>>>(in, out);
}

// Round 7
// 21.250 us; speedup vs baseline: 1.2577x; 1.0346x over previous
//
#include <hip/hip_runtime.h>

// Rate-1/2, K=7 non-recursive conv encoder, B x 4096 -> B x 8192.
// out0[t] = m[t]^m[t-2]^m[t-3]^m[t-5]^m[t-6]   (G1 = 1011011)
// out1[t] = m[t]^m[t-1]^m[t-2]^m[t-3]^m[t-6]   (G2 = 1111001)
// cw[b, 2t] = out0[t], cw[b, 2t+1] = out1[t]
//
// R7 = R6 (ballot-packed input, one dense float4 store per thread) + the
// nontemporal hint on the output store. R4/R5 A/B showed nt is worth ~1.2us
// within a fixed structure (write stream never re-read; skip L2 allocation).

#define K_BITS 4096

typedef float floatx4 __attribute__((ext_vector_type(4)));

__global__ __launch_bounds__(256) void conv_encode_kernel(
        const float* __restrict__ in, float* __restrict__ out) {
    const int gtid = blockIdx.x * 256 + threadIdx.x;
    const int wave = gtid >> 6;            // global wave id
    const int lane = threadIdx.x & 63;

    // 32 waves per row; each wave owns 128 consecutive time steps.
    const int row = wave >> 5;
    const int wt  = (wave & 31) << 7;      // base time step within row
    const float* p = in + (size_t)row * K_BITS;

    const float x0 = p[wt + lane];
    const float x1 = p[wt + 64 + lane];
    const unsigned long long s0 = __ballot(x0 != 0.0f);  // m[wt+0 .. wt+63]
    const unsigned long long s1 = __ballot(x1 != 0.0f);  // m[wt+64 .. wt+127]

    unsigned long long hist = 0;           // m[wt-6 .. wt-1], zero at row start
    if (wt > 0) {
        const float xh = p[wt - 64 + lane];
        hist = __ballot(xh != 0.0f) >> 58; // top 6 lanes
    }

    // String bit i (i = 0..133) = m[wt + i - 6].
    const unsigned long long A = (s0 << 6) | hist;         // bits 0..63
    const unsigned long long B = (s0 >> 58) | (s1 << 6);   // bits 64..127
    const unsigned long long C = (s1 >> 58);               // bits 128..133

    // Lane l emits times wt+2l, wt+2l+1; needs string bits 2l .. 2l+7.
    const unsigned s = (2 * lane) & 63;
    const unsigned long long lo = (lane < 32) ? A : B;
    const unsigned long long hi = (lane < 32) ? B : C;
    // w bit k = string bit (2*lane + k); safe 128-bit funnel (s in 0..62).
    const unsigned w =
        (unsigned)((lo >> s) | ((hi << (63 - s)) << 1));

    const unsigned y0 = (w >> 6) ^ (w >> 4) ^ (w >> 3) ^ (w >> 1) ^ w;
    const unsigned y1 = (w >> 6) ^ (w >> 5) ^ (w >> 4) ^ (w >> 3) ^ w;

    floatx4 o;
    o.x = (float)( y0       & 1u);
    o.y = (float)( y1       & 1u);
    o.z = (float)((y0 >> 1) & 1u);
    o.w = (float)((y1 >> 1) & 1u);

    // Wave's 64 lanes cover 64 consecutive output float4s (same as R2: tid*4).
    __builtin_nontemporal_store(
        o, reinterpret_cast<floatx4*>(out + (size_t)gtid * 4));
}

extern "C" void kernel_launch(void* const* d_in, const int* in_sizes, int n_in,
                              void* d_out, int out_size, void* d_ws, size_t ws_size,
                              hipStream_t stream) {
    const float* in = (const float*)d_in[0];   // [B, 4096] of 0.0/1.0
    float* out = (float*)d_out;                // [B, 8192]

    const int B = in_sizes[0] / K_BITS;        // 2048
    const int total_threads = B * (K_BITS / 2);  // one float4 out per thread
    const int blocks = total_threads / 256;      // 16384

    conv_encode_kernel<<<blocks, 256, 0, stream>>>(in, out);
}

// Round 8
// 20.280 us; speedup vs baseline: 1.3178x; 1.0478x over previous
//
#include <hip/hip_runtime.h>

// Rate-1/2, K=7 non-recursive conv encoder, B x 4096 -> B x 8192.
// out0[t] = m[t]^m[t-2]^m[t-3]^m[t-5]^m[t-6]   (G1 = 1011011)
// out1[t] = m[t]^m[t-1]^m[t-2]^m[t-3]^m[t-6]   (G2 = 1111001)
// cw[b, 2t] = out0[t], cw[b, 2t+1] = out1[t]
//
// R8: R7's ballot scheme, 2x work per wave. One wave = 256 time steps:
// 4 dense dword loads -> 4 ballots -> wave-uniform 262-bit string in 5 u64s;
// each lane extracts two 8-bit windows (shared shift) and issues two dense
// 1KB nontemporal float4 stores. Halves wave count (ramp/drain) vs R7.

#define K_BITS 4096

typedef float floatx4 __attribute__((ext_vector_type(4)));

__global__ __launch_bounds__(256) void conv_encode_kernel(
        const float* __restrict__ in, float* __restrict__ out) {
    const int gtid = blockIdx.x * 256 + threadIdx.x;
    const int wave = gtid >> 6;            // global wave id
    const int lane = threadIdx.x & 63;

    // 16 waves per row; each wave owns 256 consecutive time steps.
    const int row = wave >> 4;
    const int wt  = (wave & 15) << 8;      // base time step within row
    const float* p = in + (size_t)row * K_BITS;

    const float x0 = p[wt + lane];
    const float x1 = p[wt + 64  + lane];
    const float x2 = p[wt + 128 + lane];
    const float x3 = p[wt + 192 + lane];
    const unsigned long long s0 = __ballot(x0 != 0.0f);
    const unsigned long long s1 = __ballot(x1 != 0.0f);
    const unsigned long long s2 = __ballot(x2 != 0.0f);
    const unsigned long long s3 = __ballot(x3 != 0.0f);

    unsigned long long hist = 0;           // m[wt-6 .. wt-1], zero at row start
    if (wt > 0) {
        const float xh = p[wt - 64 + lane];
        hist = __ballot(xh != 0.0f) >> 58; // top 6 lanes
    }

    // String bit i (i = 0..261) = m[wt + i - 6].
    const unsigned long long A = (s0 << 6) | hist;
    const unsigned long long B = (s0 >> 58) | (s1 << 6);
    const unsigned long long C = (s1 >> 58) | (s2 << 6);
    const unsigned long long D = (s2 >> 58) | (s3 << 6);
    const unsigned long long E = (s3 >> 58);

    const unsigned s = (2 * lane) & 63;    // shared shift for both windows

    // Window 1: string bits 2l .. 2l+7  (times wt+2l, wt+2l+1)
    {
        const unsigned long long lo = (lane < 32) ? A : B;
        const unsigned long long hi = (lane < 32) ? B : C;
        const unsigned w = (unsigned)((lo >> s) | ((hi << (63 - s)) << 1));

        const unsigned y0 = (w >> 6) ^ (w >> 4) ^ (w >> 3) ^ (w >> 1) ^ w;
        const unsigned y1 = (w >> 6) ^ (w >> 5) ^ (w >> 4) ^ (w >> 3) ^ w;

        floatx4 o;
        o.x = (float)( y0       & 1u);
        o.y = (float)( y1       & 1u);
        o.z = (float)((y0 >> 1) & 1u);
        o.w = (float)((y1 >> 1) & 1u);
        __builtin_nontemporal_store(
            o, reinterpret_cast<floatx4*>(out + ((size_t)wave * 128 + lane) * 4));
    }

    // Window 2: string bits 128+2l .. 128+2l+7  (times wt+128+2l, wt+128+2l+1)
    {
        const unsigned long long lo = (lane < 32) ? C : D;
        const unsigned long long hi = (lane < 32) ? D : E;
        const unsigned w = (unsigned)((lo >> s) | ((hi << (63 - s)) << 1));

        const unsigned y0 = (w >> 6) ^ (w >> 4) ^ (w >> 3) ^ (w >> 1) ^ w;
        const unsigned y1 = (w >> 6) ^ (w >> 5) ^ (w >> 4) ^ (w >> 3) ^ w;

        floatx4 o;
        o.x = (float)( y0       & 1u);
        o.y = (float)( y1       & 1u);
        o.z = (float)((y0 >> 1) & 1u);
        o.w = (float)((y1 >> 1) & 1u);
        __builtin_nontemporal_store(
            o, reinterpret_cast<floatx4*>(out + ((size_t)wave * 128 + 64 + lane) * 4));
    }
}

extern "C" void kernel_launch(void* const* d_in, const int* in_sizes, int n_in,
                              void* d_out, int out_size, void* d_ws, size_t ws_size,
                              hipStream_t stream) {
    const float* in = (const float*)d_in[0];   // [B, 4096] of 0.0/1.0
    float* out = (float*)d_out;                // [B, 8192]

    const int B = in_sizes[0] / K_BITS;        // 2048
    const int total_threads = B * (K_BITS / 4);  // two float4 out per thread
    const int blocks = total_threads / 256;      // 8192

    conv_encode_kernel<<<blocks, 256, 0, stream>>>(in, out);
}

// Round 9
// 19.853 us; speedup vs baseline: 1.3462x; 1.0215x over previous
//
#include <hip/hip_runtime.h>

// Rate-1/2, K=7 non-recursive conv encoder, B x 4096 -> B x 8192.
// out0[t] = m[t]^m[t-2]^m[t-3]^m[t-5]^m[t-6]   (G1 = 1011011)
// out1[t] = m[t]^m[t-1]^m[t-2]^m[t-3]^m[t-6]   (G2 = 1111001)
// cw[b, 2t] = out0[t], cw[b, 2t+1] = out1[t]
//
// R9: ballot scheme, 4x work per wave vs R7. One wave = 512 time steps:
// 8 dense dword loads -> 8 ballots -> wave-uniform 518-bit string in 9 u64s;
// each lane extracts four 8-bit windows (one shared shift amount) and issues
// four dense 1KB nontemporal float4 stores.

#define K_BITS 4096

typedef float floatx4 __attribute__((ext_vector_type(4)));

__global__ __launch_bounds__(256) void conv_encode_kernel(
        const float* __restrict__ in, float* __restrict__ out) {
    const int gtid = blockIdx.x * 256 + threadIdx.x;
    const int wave = gtid >> 6;            // global wave id
    const int lane = threadIdx.x & 63;

    // 8 waves per row; each wave owns 512 consecutive time steps.
    const int row = wave >> 3;
    const int wt  = (wave & 7) << 9;       // base time step within row
    const float* p = in + (size_t)row * K_BITS;

    unsigned long long s[8];
#pragma unroll
    for (int k = 0; k < 8; ++k) {
        const float x = p[wt + 64 * k + lane];
        s[k] = __ballot(x != 0.0f);        // bit l = m[wt + 64k + l]
    }

    unsigned long long hist = 0;           // m[wt-6 .. wt-1], zero at row start
    if (wt > 0) {
        const float xh = p[wt - 64 + lane];
        hist = __ballot(xh != 0.0f) >> 58; // top 6 lanes
    }

    // String bit i (i = 0..517) = m[wt + i - 6].
    unsigned long long W[9];
    W[0] = (s[0] << 6) | hist;
#pragma unroll
    for (int k = 1; k < 8; ++k) W[k] = (s[k - 1] >> 58) | (s[k] << 6);
    W[8] = s[7] >> 58;

    const unsigned sh  = (2 * lane) & 63;  // shared shift for all 4 windows
    const int      sel = (lane >= 32) ? 1 : 0;

    // Window j: string bits 128j+2l .. 128j+2l+7 -> times wt+128j+2l, +1.
#pragma unroll
    for (int j = 0; j < 4; ++j) {
        const unsigned long long lo = W[2 * j + sel];
        const unsigned long long hi = W[2 * j + 1 + sel];
        const unsigned w = (unsigned)((lo >> sh) | ((hi << (63 - sh)) << 1));

        const unsigned y0 = (w >> 6) ^ (w >> 4) ^ (w >> 3) ^ (w >> 1) ^ w;
        const unsigned y1 = (w >> 6) ^ (w >> 5) ^ (w >> 4) ^ (w >> 3) ^ w;

        floatx4 o;
        o.x = (float)( y0       & 1u);
        o.y = (float)( y1       & 1u);
        o.z = (float)((y0 >> 1) & 1u);
        o.w = (float)((y1 >> 1) & 1u);
        __builtin_nontemporal_store(
            o, reinterpret_cast<floatx4*>(
                   out + ((size_t)wave * 256 + 64 * j + lane) * 4));
    }
}

extern "C" void kernel_launch(void* const* d_in, const int* in_sizes, int n_in,
                              void* d_out, int out_size, void* d_ws, size_t ws_size,
                              hipStream_t stream) {
    const float* in = (const float*)d_in[0];   // [B, 4096] of 0.0/1.0
    float* out = (float*)d_out;                // [B, 8192]

    const int B = in_sizes[0] / K_BITS;        // 2048
    const int total_threads = B * (K_BITS / 8);  // four float4 out per thread
    const int blocks = total_threads / 256;      // 4096

    conv_encode_kernel<<<blocks, 256, 0, stream>>>(in, out);
}

// Round 10
// 18.465 us; speedup vs baseline: 1.4474x; 1.0752x over previous
//
#include <hip/hip_runtime.h>

// Rate-1/2, K=7 non-recursive conv encoder, B x 4096 -> B x 8192.
// out0[t] = m[t]^m[t-2]^m[t-3]^m[t-5]^m[t-6]   (G1 = 1011011)
// out1[t] = m[t]^m[t-1]^m[t-2]^m[t-3]^m[t-6]   (G2 = 1111001)
// cw[b, 2t] = out0[t], cw[b, 2t+1] = out1[t]
//
// R10: ballot scheme, 1024 time steps per wave -> 8192 waves total = exactly
// ONE occupancy pass (R9's 16384 waves = 2 passes, double ramp/drain).
// One block (4 waves) = one row. 16 dense dword loads + 1 history load ->
// 17 ballots -> wave-uniform 1030-bit string in 17 SGPR u64s; each lane
// extracts eight 8-bit windows (one shared shift) -> 8 dense 1KB nt stores.

#define K_BITS 4096

typedef float floatx4 __attribute__((ext_vector_type(4)));

__global__ __launch_bounds__(256) void conv_encode_kernel(
        const float* __restrict__ in, float* __restrict__ out) {
    const int lane   = threadIdx.x & 63;
    const int wslot  = threadIdx.x >> 6;     // wave within block (0..3)
    const int row    = blockIdx.x;           // one row per block
    const int wt     = wslot << 10;          // base time step within row

    const float* p = in + (size_t)row * K_BITS;

    unsigned long long s[16];
#pragma unroll
    for (int k = 0; k < 16; ++k) {
        const float x = p[wt + 64 * k + lane];
        s[k] = __ballot(x != 0.0f);          // bit l = m[wt + 64k + l]
    }

    unsigned long long hist = 0;             // m[wt-6 .. wt-1], 0 at row start
    if (wt > 0) {
        const float xh = p[wt - 64 + lane];
        hist = __ballot(xh != 0.0f) >> 58;   // top 6 lanes
    }

    // String bit i (i = 0..1029) = m[wt + i - 6].
    unsigned long long W[17];
    W[0] = (s[0] << 6) | hist;
#pragma unroll
    for (int k = 1; k < 16; ++k) W[k] = (s[k - 1] >> 58) | (s[k] << 6);
    W[16] = s[15] >> 58;

    const unsigned sh  = (2 * lane) & 63;    // shared shift for all 8 windows
    const int      sel = (lane >= 32) ? 1 : 0;

    // Window j: string bits 128j+2l .. 128j+2l+7 -> times wt+128j+2l, +1.
#pragma unroll
    for (int j = 0; j < 8; ++j) {
        const unsigned long long lo = W[2 * j + sel];
        const unsigned long long hi = W[2 * j + 1 + sel];
        const unsigned w = (unsigned)((lo >> sh) | ((hi << (63 - sh)) << 1));

        const unsigned y0 = (w >> 6) ^ (w >> 4) ^ (w >> 3) ^ (w >> 1) ^ w;
        const unsigned y1 = (w >> 6) ^ (w >> 5) ^ (w >> 4) ^ (w >> 3) ^ w;

        floatx4 o;
        o.x = (float)( y0       & 1u);
        o.y = (float)( y1       & 1u);
        o.z = (float)((y0 >> 1) & 1u);
        o.w = (float)((y1 >> 1) & 1u);
        __builtin_nontemporal_store(
            o, reinterpret_cast<floatx4*>(
                   out + ((size_t)row * 2048 + (size_t)wslot * 512
                          + 64 * j + lane) * 4));
    }
}

extern "C" void kernel_launch(void* const* d_in, const int* in_sizes, int n_in,
                              void* d_out, int out_size, void* d_ws, size_t ws_size,
                              hipStream_t stream) {
    const float* in = (const float*)d_in[0];   // [B, 4096] of 0.0/1.0
    float* out = (float*)d_out;                // [B, 8192]

    const int B = in_sizes[0] / K_BITS;        // 2048 rows = 2048 blocks
    conv_encode_kernel<<<B, 256, 0, stream>>>(in, out);
}